// Round 2
// baseline (5845.792 us; speedup 1.0000x reference)
//
#include <hip/hip_runtime.h>

// WeatherLSTM: B=256, T=128, I=64, H=2048, O=24
// g = [h|x] @ Wcat + b ; i,f,o,c gates ; 151 sequential steps.
// Wp packed as [p][k] (B^T), p = u*4 + gate, k in [0,2112).
// R2: BM=256 (full batch) x BN=32 per block -> Wp read 1x/step (from L3),
//     activations [h|x] (1.08 MB) carry the redundancy but are L2-resident.

#define NB 256
#define NH 2048
#define NI 64
#define NK 2112      // NH + NI
#define NPK 8192     // 4*NH
#define NSTEPS 151   // 128 encoder + 23 decoder
#define NO 24

typedef __bf16 bf16x8 __attribute__((ext_vector_type(8)));
typedef short short8 __attribute__((ext_vector_type(8)));
typedef float f32x4 __attribute__((ext_vector_type(4)));
typedef unsigned short u16;

__device__ __forceinline__ u16 f2bf(float f) {
  union { float f; unsigned u; } v; v.f = f;
  unsigned r = v.u + 0x7FFFu + ((v.u >> 16) & 1u);  // RNE
  return (u16)(r >> 16);
}

__device__ __forceinline__ void gload16(const void* g, void* l) {
  __builtin_amdgcn_global_load_lds(
      (const __attribute__((address_space(1))) unsigned int*)g,
      (__attribute__((address_space(3))) unsigned int*)l, 16, 0, 0);
}

__device__ __forceinline__ float sigmoidf_(float x) {
  return 1.f / (1.f + __expf(-x));
}
__device__ __forceinline__ float tanhf_(float x) {
  x = fminf(15.f, fmaxf(-15.f, x));
  float e = __expf(2.f * x);
  return (e - 1.f) / (e + 1.f);
}

// ---- pack [Wh;Wx] fp32 [k][4H] -> Wp bf16 [p][k], p = u*4+g, via LDS transpose tile
__global__ __launch_bounds__(256) void wl_pack_w(const float* __restrict__ Wx,
                                                 const float* __restrict__ Wh,
                                                 u16* __restrict__ Wp) {
  __shared__ float s[64][65];
  const int j0 = blockIdx.x * 64, k0 = blockIdx.y * 64;
  const int tid = threadIdx.x;
  const int jl = tid & 63, kg = tid >> 6;  // kg in 0..3
#pragma unroll
  for (int it = 0; it < 16; ++it) {
    int kl = it * 4 + kg;
    int k = k0 + kl, j = j0 + jl;
    float v = (k < NH) ? Wh[(size_t)k * NPK + j] : Wx[(size_t)(k - NH) * NPK + j];
    s[kl][jl] = v;
  }
  __syncthreads();
  int j = j0 + jl;
  int p = (j & (NH - 1)) * 4 + (j >> 11);  // u*4 + gate
  short8 v0, v1;
#pragma unroll
  for (int e = 0; e < 8; ++e) {
    v0[e] = (short)f2bf(s[kg * 16 + e][jl]);
    v1[e] = (short)f2bf(s[kg * 16 + 8 + e][jl]);
  }
  short8* dst = (short8*)(Wp + (size_t)p * NK + k0 + kg * 16);
  dst[0] = v0;
  dst[1] = v1;
}

// ---- bsum[p] = bx[j] + bh[j]
__global__ __launch_bounds__(256) void wl_bsum(const float* __restrict__ bx,
                                               const float* __restrict__ bh,
                                               float* __restrict__ bsum) {
  int p = blockIdx.x * 256 + threadIdx.x;
  int j = (p & 3) * NH + (p >> 2);
  bsum[p] = bx[j] + bh[j];
}

// ---- xall[t][b][i] bf16: encoder = trains, decoder = dec*Win + b_in
__global__ __launch_bounds__(256) void wl_xall(const float* __restrict__ trains,
                                               const float* __restrict__ dec,
                                               const float* __restrict__ Win,
                                               const float* __restrict__ b_in,
                                               u16* __restrict__ xall) {
  int idx = blockIdx.x * 256 + threadIdx.x;
  int i = idx & 63;
  int b = (idx >> 6) & 255;
  int t = idx >> 14;
  float v;
  if (t < 128)
    v = trains[((size_t)b * 128 + t) * 64 + i];
  else
    v = dec[b * 23 + (t - 128)] * Win[i] + b_in[i];
  xall[idx] = f2bf(v);
}

// ---- one LSTM step. grid 256 blocks (1/CU), 256 threads (4 waves).
// Block bn: packed cols [bn*32, bn*32+32) = 8 hidden units, ALL 256 batch rows.
// K loop 33 x BK=64. A tile 256x64 (32KB), B tile 32x64 (4KB), double-buffered,
// XOR-swizzled (pre-swizzled global source), counted vmcnt(9).
__global__ __launch_bounds__(256) void wl_step(const u16* __restrict__ Wp,
                                               const float* __restrict__ bsum,
                                               const u16* __restrict__ xall,
                                               u16* __restrict__ hcat,   // 2 buffers
                                               float* __restrict__ c_t,  // [unit][b]
                                               float* __restrict__ ypart,
                                               const float* __restrict__ Wout,
                                               int t) {
  __shared__ char arena[73728];  // A0 32K | A1 32K | B0 4K | B1 4K ; epilogue gtile 32x260 f32

  const int bn = blockIdx.x;     // 0..255
  const int p0 = bn * 32;
  const int tid = threadIdx.x;
  const int wv = tid >> 6, lane = tid & 63;
  const int l15 = lane & 15, lhi = lane >> 4;
  const int srow = lane >> 3;                 // 0..7
  const int g8 = (lane & 7) ^ srow;           // pre-swizzled 16B chunk index

  const u16* __restrict__ hin = hcat + (size_t)(t & 1) * NB * NH;
  u16* __restrict__ hout = hcat + (size_t)((t + 1) & 1) * NB * NH;

  f32x4 acc[4][2] = {};

  auto stage = [&](int kt, int buf) {
    // A: [h|x] rows 0..255, k-slice kt*64..+64 -> 32 KB
    const u16* asrc;
    size_t astr;
    if (kt < 32) { asrc = hin + (size_t)kt * 64;        astr = NH; }
    else         { asrc = xall + (size_t)t * NB * NI;   astr = NI; }
#pragma unroll
    for (int i = 0; i < 8; ++i) {
      int qa = wv * 8 + i;              // 1KB chunk id 0..31
      int row = qa * 8 + srow;          // batch row 0..255 ; row&7 == srow
      gload16(asrc + (size_t)row * astr + g8 * 8, arena + buf * 32768 + qa * 1024);
    }
    // B: 32 packed cols x 64 k -> 4 KB (1 load/thread)
    const u16* bsrc = Wp + (size_t)p0 * NK + (size_t)kt * 64;
    int col = wv * 8 + srow;            // 0..31 ; col&7 == srow
    gload16(bsrc + (size_t)col * NK + g8 * 8, arena + 65536 + buf * 4096 + wv * 1024);
  };

  stage(0, 0);
  for (int kt = 0; kt < 33; ++kt) {
    const int buf = kt & 1;
    if (kt < 32) {
      stage(kt + 1, buf ^ 1);
      asm volatile("s_waitcnt vmcnt(9)" ::: "memory");  // current tile's 9 loads done
    } else {
      asm volatile("s_waitcnt vmcnt(0)" ::: "memory");
    }
    __syncthreads();
    const char* Ab = arena + buf * 32768;
    const char* Bb = arena + 65536 + buf * 4096;
#pragma unroll
    for (int kc = 0; kc < 2; ++kc) {
      const int c8 = kc * 4 + lhi;
      bf16x8 bfr[2];
#pragma unroll
      for (int n = 0; n < 2; ++n) {
        int col = n * 16 + l15;
        bfr[n] = *(const bf16x8*)(Bb + col * 128 + ((c8 ^ (col & 7)) << 4));
      }
#pragma unroll
      for (int m = 0; m < 4; ++m) {
        int row = wv * 64 + m * 16 + l15;
        bf16x8 afr = *(const bf16x8*)(Ab + row * 128 + ((c8 ^ (row & 7)) << 4));
#pragma unroll
        for (int n = 0; n < 2; ++n)
          acc[m][n] = __builtin_amdgcn_mfma_f32_16x16x32_bf16(afr, bfr[n], acc[m][n], 0, 0, 0);
      }
    }
    __syncthreads();
  }

  // spill acc -> LDS gtile[col 0..31][row 0..255] (stride 260), f32x4 per (m,n)
  // C/D layout: col = n*16 + (lane&15), rows = wv*64 + m*16 + (lane>>4)*4 + r
  float* gtile = (float*)arena;
#pragma unroll
  for (int m = 0; m < 4; ++m)
#pragma unroll
    for (int n = 0; n < 2; ++n) {
      int col = n * 16 + l15;
      int row = wv * 64 + m * 16 + lhi * 4;
      *(f32x4*)(gtile + col * 260 + row) = acc[m][n];
    }
  __syncthreads();

  // gates + state update: thread = batch row b, 8 units in-thread.
  const int b = tid;
  const bool emit = (t >= 127);
  f32x4 c0 = *(const f32x4*)(c_t + ((size_t)bn * 8 + 0) * 0);  // placeholder no
  // c_t layout [unit 0..2047][b 0..255]; our units: bn*8+u
  float yacc = 0.f;
  short8 hv;
  float cn_arr0[4], cn_arr1[4];
#pragma unroll
  for (int u = 0; u < 8; ++u) {
    int p = u * 4;
    float gi = gtile[(p + 0) * 260 + b] + bsum[p0 + p + 0];
    float gf = gtile[(p + 1) * 260 + b] + bsum[p0 + p + 1];
    float go = gtile[(p + 2) * 260 + b] + bsum[p0 + p + 2];
    float gc = gtile[(p + 3) * 260 + b] + bsum[p0 + p + 3];
    float si = sigmoidf_(gi), sf = sigmoidf_(gf), so = sigmoidf_(go), tc = tanhf_(gc);
    float cold = c_t[((size_t)bn * 8 + u) * NB + b];
    float cn = sf * cold + si * tc;
    float h = so * tanhf_(cn);
    c_t[((size_t)bn * 8 + u) * NB + b] = cn;
    hv[u] = (short)f2bf(h);
    if (emit) yacc += h * Wout[bn * 8 + u];
  }
  (void)c0; (void)cn_arr0; (void)cn_arr1;
  *(short8*)(hout + (size_t)b * NH + bn * 8) = hv;  // 16B store per thread
  if (emit) ypart[(((size_t)(t - 127)) * NB + bn) * NB + b] = yacc;
}

// ---- y[b][j] = bout + sum_bn ypart[j][bn][b]
__global__ __launch_bounds__(256) void wl_finy(const float* __restrict__ ypart,
                                               const float* __restrict__ bout,
                                               float* __restrict__ out) {
  int j = blockIdx.x;
  int b = threadIdx.x;
  const float* yp = ypart + (size_t)j * NB * NB;
  float s = bout[0];
#pragma unroll 8
  for (int i = 0; i < 256; ++i) s += yp[i * 256 + b];
  out[b * NO + j] = s;
}

extern "C" void kernel_launch(void* const* d_in, const int* in_sizes, int n_in,
                              void* d_out, int out_size, void* d_ws, size_t ws_size,
                              hipStream_t stream) {
  const float* trains = (const float*)d_in[0];
  const float* dec    = (const float*)d_in[1];
  const float* Wx     = (const float*)d_in[2];
  const float* bx     = (const float*)d_in[3];
  const float* Wh     = (const float*)d_in[4];
  const float* bh     = (const float*)d_in[5];
  const float* Win    = (const float*)d_in[6];
  const float* b_in   = (const float*)d_in[7];
  const float* Wout   = (const float*)d_in[8];
  const float* bout   = (const float*)d_in[9];
  float* out = (float*)d_out;
  char* ws = (char*)d_ws;

  u16*   Wp      = (u16*)(ws);                    // 34,603,008 B
  float* bsum    = (float*)(ws + 34603008);       //     32,768 B
  u16*   xall    = (u16*)(ws + 34635776);         //  4,947,968 B
  u16*   hcat    = (u16*)(ws + 39583744);         //  2,097,152 B (double-buffered h)
  float* c_t     = (float*)(ws + 41680896);       //  2,097,152 B ([unit][b] fp32)
  float* ypart   = (float*)(ws + 43778048);       //  6,291,456 B   total ~50 MB

  // zero h (both buffers) + c
  hipMemsetAsync(ws + 39583744, 0, 4194304, stream);
  wl_pack_w<<<dim3(128, 33), 256, 0, stream>>>(Wx, Wh, Wp);
  wl_bsum<<<32, 256, 0, stream>>>(bx, bh, bsum);
  wl_xall<<<(NSTEPS * NB * NI) / 256, 256, 0, stream>>>(trains, dec, Win, b_in, xall);
  for (int t = 0; t < NSTEPS; ++t)
    wl_step<<<256, 256, 0, stream>>>(Wp, bsum, xall, hcat, c_t, ypart, Wout, t);
  wl_finy<<<NO, 256, 0, stream>>>(ypart, bout, out);
}